// Round 1
// baseline (1039.448 us; speedup 1.0000x reference)
//
#include <hip/hip_runtime.h>
#include <hip/hip_bf16.h>

#define N_NODES 50000
#define N_EDGES 600000
#define DIM     128
#define HID     256
#define NGRAPH  512
#define LN_EPS  1e-5f

typedef __attribute__((ext_vector_type(8))) short bf16x8;
typedef __attribute__((ext_vector_type(4))) float f32x4;

__device__ __forceinline__ unsigned short f2bf(float x) {
  unsigned int u = __builtin_bit_cast(unsigned int, x);
  unsigned int r = (u + 0x7FFFu + ((u >> 16) & 1u)) >> 16;
  return (unsigned short)r;
}

// ---------------- zero / counts ----------------
__global__ void k_zero_acc(float4* __restrict__ acc) {
  size_t i = (size_t)blockIdx.x * blockDim.x + threadIdx.x;
  acc[i] = make_float4(0.f, 0.f, 0.f, 0.f);
}

__global__ void k_zero_counts(int* __restrict__ counts) {
  int i = threadIdx.x;
  if (i < NGRAPH) counts[i] = 0;
}

__global__ void k_counts(const int* __restrict__ node_id, int* __restrict__ counts) {
  int i = blockIdx.x * 256 + threadIdx.x;
  if (i < N_NODES) atomicAdd(&counts[node_id[i]], 1);
}

// ---------------- weight prep: W1^T, W2^T as swizzled bf16 blob ----------------
// blob layout:
//   [0, 65536):      W1T row c (0..255), 128 bf16/row, byte = c*256 + ((2k)^((c&7)<<4))
//   [65536, 131072): W2T row c (0..127), 256 bf16/row, byte = 65536 + c*512 + ((2k)^((c&7)<<4))
__global__ void k_prep_weights(const float* __restrict__ W1, const float* __restrict__ W2,
                               unsigned char* __restrict__ blob) {
  int id = blockIdx.x * 256 + threadIdx.x; // 0..8191
  union { unsigned short s[8]; uint4 v; } u;
  if (id < 4096) {
    int c  = id >> 4;        // 0..255
    int k0 = (id & 15) * 8;  // 0..120
#pragma unroll
    for (int j = 0; j < 8; ++j) u.s[j] = f2bf(W1[(size_t)(k0 + j) * HID + c]);
    unsigned char* dst = blob + c * 256 + ((k0 * 2) ^ ((c & 7) << 4));
    *(uint4*)dst = u.v;
  } else if (id < 8192) {
    int id2 = id - 4096;
    int c  = id2 >> 5;        // 0..127
    int k0 = (id2 & 31) * 8;  // 0..248
#pragma unroll
    for (int j = 0; j < 8; ++j) u.s[j] = f2bf(W2[(size_t)(k0 + j) * DIM + c]);
    unsigned char* dst = blob + 65536 + c * 512 + ((k0 * 2) ^ ((c & 7) << 4));
    *(uint4*)dst = u.v;
  }
}

// ---------------- edge scatter: acc += relu(nh[src] + eh[e]) at dst ----------------
__global__ void k_edges(const float4* __restrict__ nh4, const float4* __restrict__ eh4,
                        const int* __restrict__ ei, float* __restrict__ acc) {
  int t = blockIdx.x * 256 + threadIdx.x;
  int e = t >> 5;
  int q = t & 31;
  if (e >= N_EDGES) return;
  int src = ei[e];
  int dst = ei[N_EDGES + e];
  float4 a = nh4[(size_t)src * 32 + q];
  float4 b = eh4[(size_t)e * 32 + q];
  float m0 = fmaxf(a.x + b.x, 0.f);
  float m1 = fmaxf(a.y + b.y, 0.f);
  float m2 = fmaxf(a.z + b.z, 0.f);
  float m3 = fmaxf(a.w + b.w, 0.f);
  float* p = acc + (size_t)dst * DIM + q * 4;
  if (m0 > 0.f) atomicAdd(p + 0, m0);
  if (m1 > 0.f) atomicAdd(p + 1, m1);
  if (m2 > 0.f) atomicAdd(p + 2, m2);
  if (m3 > 0.f) atomicAdd(p + 3, m3);
}

// ---------------- fused MLP + LayerNorm + GraphNorm + ReLU + residual ----------------
// acc (= d_out, in place): rows contain agg (h = nh + agg done at load time)
__global__ __launch_bounds__(512, 2) void k_mlp(
    const float* acc, const float* __restrict__ nh,
    const unsigned char* __restrict__ blob,
    const float* __restrict__ b1v, const float* __restrict__ b2v,
    const float* __restrict__ gam, const float* __restrict__ bet,
    const int* __restrict__ node_id, const int* __restrict__ counts,
    float* outp) {
  __shared__ unsigned char lds[131072];
  const int tid  = threadIdx.x;
  const int lane = tid & 63;
  const int wave = tid >> 6;
  const int l15  = lane & 15;
  const int lhi  = lane >> 4;      // 0..3
  const int swz  = (lane & 7) << 4;

  // stage 128KB of pre-swizzled weights (linear copy)
  {
    const uint4* s = (const uint4*)blob;
    uint4* d = (uint4*)lds;
#pragma unroll
    for (int i = 0; i < 16; ++i) d[tid + i * 512] = s[tid + i * 512];
  }
  __syncthreads();

  const int row0 = blockIdx.x * 128 + wave * 16; // wave's 16 rows
  const int arow = row0 + l15;
  const bool aok = arow < N_NODES;
  const float* ap = acc + (size_t)arow * DIM + lhi * 8;
  const float* np = nh + (size_t)arow * DIM + lhi * 8;

  // ---- GEMM1: [16x128] x [128x256] ----
  f32x4 c1[16];
#pragma unroll
  for (int i = 0; i < 16; ++i) c1[i] = (f32x4){0.f, 0.f, 0.f, 0.f};

#pragma unroll
  for (int ks = 0; ks < 4; ++ks) {
    bf16x8 af;
    if (aok) {
      float4 x0 = *(const float4*)(ap + ks * 32);
      float4 x1 = *(const float4*)(ap + ks * 32 + 4);
      float4 y0 = *(const float4*)(np + ks * 32);
      float4 y1 = *(const float4*)(np + ks * 32 + 4);
      af[0] = (short)f2bf(x0.x + y0.x);
      af[1] = (short)f2bf(x0.y + y0.y);
      af[2] = (short)f2bf(x0.z + y0.z);
      af[3] = (short)f2bf(x0.w + y0.w);
      af[4] = (short)f2bf(x1.x + y1.x);
      af[5] = (short)f2bf(x1.y + y1.y);
      af[6] = (short)f2bf(x1.z + y1.z);
      af[7] = (short)f2bf(x1.w + y1.w);
    } else {
#pragma unroll
      for (int j = 0; j < 8; ++j) af[j] = 0;
    }
#pragma unroll
    for (int ct = 0; ct < 16; ++ct) {
      int c = ct * 16 + l15;
      const bf16x8* bp = (const bf16x8*)(lds + c * 256 + ((ks * 64 + lhi * 16) ^ swz));
      c1[ct] = __builtin_amdgcn_mfma_f32_16x16x32_bf16(af, *bp, c1[ct], 0, 0, 0);
    }
  }
  __syncthreads(); // all waves done reading W1T region

  // ---- h1 = relu(c1 + b1) -> bf16, swizzled, into per-wave LDS region ----
  unsigned char* hb = lds + wave * 8192; // 16 rows x 512B
#pragma unroll
  for (int ct = 0; ct < 16; ++ct) {
    int c = ct * 16 + l15;
    float bb = b1v[c];
#pragma unroll
    for (int i = 0; i < 4; ++i) {
      int r = lhi * 4 + i;
      float v = fmaxf(c1[ct][i] + bb, 0.f);
      *(unsigned short*)(hb + r * 512 + ((2 * c) ^ ((r & 7) << 4))) = f2bf(v);
    }
  }
  __syncthreads();

  // ---- GEMM2: [16x256] x [256x128] ----
  f32x4 c2[8];
#pragma unroll
  for (int i = 0; i < 8; ++i) c2[i] = (f32x4){0.f, 0.f, 0.f, 0.f};

#pragma unroll
  for (int ks = 0; ks < 8; ++ks) {
    bf16x8 af = *(const bf16x8*)(hb + l15 * 512 + ((ks * 64 + lhi * 16) ^ swz));
#pragma unroll
    for (int ct = 0; ct < 8; ++ct) {
      int c = ct * 16 + l15;
      const bf16x8* bp = (const bf16x8*)(lds + 65536 + c * 512 + ((ks * 64 + lhi * 16) ^ swz));
      c2[ct] = __builtin_amdgcn_mfma_f32_16x16x32_bf16(af, *bp, c2[ct], 0, 0, 0);
    }
  }

  // ---- epilogue: +b2, LayerNorm, GraphNorm, ReLU, +residual ----
  float vbuf[8][4];
  float s[4] = {0.f, 0.f, 0.f, 0.f}, sq[4] = {0.f, 0.f, 0.f, 0.f};
#pragma unroll
  for (int ct = 0; ct < 8; ++ct) {
    float bb = b2v[ct * 16 + l15];
#pragma unroll
    for (int i = 0; i < 4; ++i) {
      float x = c2[ct][i] + bb;
      vbuf[ct][i] = x;
      s[i] += x;
      sq[i] += x * x;
    }
  }
#pragma unroll
  for (int m = 1; m <= 8; m <<= 1) {
#pragma unroll
    for (int i = 0; i < 4; ++i) {
      s[i] += __shfl_xor(s[i], m, 64);
      sq[i] += __shfl_xor(sq[i], m, 64);
    }
  }
  float mu[4], rstd[4], gs[4];
  int rr[4];
  bool rok[4];
#pragma unroll
  for (int i = 0; i < 4; ++i) {
    mu[i] = s[i] * (1.f / 128.f);
    float var = sq[i] * (1.f / 128.f) - mu[i] * mu[i];
    rstd[i] = rsqrtf(var + LN_EPS);
    rr[i] = row0 + lhi * 4 + i;
    rok[i] = rr[i] < N_NODES;
    int g = rok[i] ? node_id[rr[i]] : 0;
    gs[i] = rsqrtf(fmaxf((float)counts[g], 1.f));
  }
#pragma unroll
  for (int ct = 0; ct < 8; ++ct) {
    int c = ct * 16 + l15;
    float gg = gam[c], be = bet[c];
#pragma unroll
    for (int i = 0; i < 4; ++i) {
      if (rok[i]) {
        float y = (vbuf[ct][i] - mu[i]) * rstd[i] * gg + be;
        y *= gs[i];
        y = fmaxf(y, 0.f);
        y += nh[(size_t)rr[i] * DIM + c];
        outp[(size_t)rr[i] * DIM + c] = y;
      }
    }
  }
}

extern "C" void kernel_launch(void* const* d_in, const int* in_sizes, int n_in,
                              void* d_out, int out_size, void* d_ws, size_t ws_size,
                              hipStream_t stream) {
  const float* node_hidden = (const float*)d_in[0];
  const float* edge_hidden = (const float*)d_in[1];
  const float* W1  = (const float*)d_in[2];
  const float* b1  = (const float*)d_in[3];
  const float* W2  = (const float*)d_in[4];
  const float* b2  = (const float*)d_in[5];
  const float* lng = (const float*)d_in[6];
  const float* lnb = (const float*)d_in[7];
  const int* edge_index = (const int*)d_in[8];
  const int* node_id    = (const int*)d_in[9];
  float* out = (float*)d_out;

  unsigned char* ws = (unsigned char*)d_ws;
  unsigned char* blob = ws;              // 128KB
  int* counts = (int*)(ws + 131072);     // 2KB

  // zero aggregation buffer (d_out doubles as accumulator) and counts
  k_zero_acc<<<6250, 256, 0, stream>>>((float4*)out);          // 6250*256*16B = 25.6MB exact
  k_zero_counts<<<1, 512, 0, stream>>>(counts);
  k_prep_weights<<<32, 256, 0, stream>>>(W1, W2, blob);
  k_counts<<<196, 256, 0, stream>>>(node_id, counts);
  k_edges<<<75000, 256, 0, stream>>>((const float4*)node_hidden,
                                     (const float4*)edge_hidden, edge_index, out);
  k_mlp<<<391, 512, 0, stream>>>(out, node_hidden, blob, b1, b2, lng, lnb,
                                 node_id, counts, out);
}

// Round 2
// 215.516 us; speedup vs baseline: 4.8231x; 4.8231x over previous
//
#include <hip/hip_runtime.h>
#include <hip/hip_bf16.h>

#define N_NODES 50000
#define N_EDGES 600000
#define DIM     128
#define HID     256
#define NGRAPH  512
#define LN_EPS  1e-5f
#define CAP     40      // slot capacity per node (Poisson(12) degree; fallback below)
#define OVFCAP  4096

typedef __attribute__((ext_vector_type(8))) short bf16x8;
typedef __attribute__((ext_vector_type(4))) float f32x4;

__device__ __forceinline__ unsigned short f2bf(float x) {
  unsigned int u = __builtin_bit_cast(unsigned int, x);
  unsigned int r = (u + 0x7FFFu + ((u >> 16) & 1u)) >> 16;
  return (unsigned short)r;
}

// ---------------- init: zero deg / counts / ovf_cnt ----------------
__global__ void k_init(int* __restrict__ deg, int* __restrict__ counts,
                       int* __restrict__ ovf_cnt) {
  int i = blockIdx.x * 256 + threadIdx.x;
  if (i < N_NODES) deg[i] = 0;
  if (i < NGRAPH) counts[i] = 0;
  if (i == 0) *ovf_cnt = 0;
}

// ---------------- weight prep: W1^T, W2^T as swizzled bf16 blob ----------------
__global__ void k_prep_weights(const float* __restrict__ W1, const float* __restrict__ W2,
                               unsigned char* __restrict__ blob) {
  int id = blockIdx.x * 256 + threadIdx.x; // 0..8191
  union { unsigned short s[8]; uint4 v; } u;
  if (id < 4096) {
    int c  = id >> 4;        // 0..255
    int k0 = (id & 15) * 8;  // 0..120
#pragma unroll
    for (int j = 0; j < 8; ++j) u.s[j] = f2bf(W1[(size_t)(k0 + j) * HID + c]);
    unsigned char* dst = blob + c * 256 + ((k0 * 2) ^ ((c & 7) << 4));
    *(uint4*)dst = u.v;
  } else if (id < 8192) {
    int id2 = id - 4096;
    int c  = id2 >> 5;        // 0..127
    int k0 = (id2 & 31) * 8;  // 0..248
#pragma unroll
    for (int j = 0; j < 8; ++j) u.s[j] = f2bf(W2[(size_t)(k0 + j) * DIM + c]);
    unsigned char* dst = blob + 65536 + c * 512 + ((k0 * 2) ^ ((c & 7) << 4));
    *(uint4*)dst = u.v;
  }
}

// ---------------- bucket build (+ graph counts histogram) ----------------
__global__ void k_scatter(const int* __restrict__ ei, const int* __restrict__ node_id,
                          int* __restrict__ deg, int* __restrict__ slots,
                          int* __restrict__ counts, int* __restrict__ ovf_cnt,
                          int* __restrict__ ovf_list) {
  int t = blockIdx.x * 256 + threadIdx.x;
  if (t < N_NODES) atomicAdd(&counts[node_id[t]], 1);
  if (t < N_EDGES) {
    int dst = ei[N_EDGES + t];
    int pos = atomicAdd(&deg[dst], 1);
    if (pos < CAP) {
      slots[(size_t)dst * CAP + pos] = t;
    } else {
      int o = atomicAdd(ovf_cnt, 1);
      if (o < OVFCAP) ovf_list[o] = t;
    }
  }
}

// ---------------- gather: agg[n] = sum_{e->n} relu(nh[src]+eh[e]) ----------------
__global__ __launch_bounds__(256) void k_gather(
    const float2* __restrict__ nh2, const float2* __restrict__ eh2,
    const int* __restrict__ ei, const int* __restrict__ deg,
    const int* __restrict__ slots, float2* __restrict__ out2) {
  int node = blockIdx.x * 4 + (threadIdx.x >> 6);
  int lane = threadIdx.x & 63;
  if (node >= N_NODES) return;
  int d = deg[node];
  if (d > CAP) d = CAP;
  int e = 0, s = 0;
  if (lane < d) {
    e = slots[(size_t)node * CAP + lane];
    s = ei[e]; // src
  }
  float2 acc = make_float2(0.f, 0.f);
  for (int i = 0; i < d; ++i) {
    int ee = __shfl(e, i);
    int ss = __shfl(s, i);
    float2 x = nh2[(size_t)ss * 64 + lane];
    float2 y = eh2[(size_t)ee * 64 + lane];
    acc.x += fmaxf(x.x + y.x, 0.f);
    acc.y += fmaxf(x.y + y.y, 0.f);
  }
  out2[(size_t)node * 64 + lane] = acc;
}

// ---------------- overflow fallback (expected count: 0) ----------------
__global__ void k_ovf(const int* __restrict__ ovf_list, const int* __restrict__ ovf_cnt,
                      const float4* __restrict__ nh4, const float4* __restrict__ eh4,
                      const int* __restrict__ ei, float* __restrict__ acc) {
  int cnt = *ovf_cnt;
  if (cnt > OVFCAP) cnt = OVFCAP;
  int t = blockIdx.x * 256 + threadIdx.x;
  int q = t & 31;
  for (int idx = t >> 5; idx < cnt; idx += (16 * 256) >> 5) {
    int e = ovf_list[idx];
    int src = ei[e];
    int dst = ei[N_EDGES + e];
    float4 a = nh4[(size_t)src * 32 + q];
    float4 b = eh4[(size_t)e * 32 + q];
    float m0 = fmaxf(a.x + b.x, 0.f);
    float m1 = fmaxf(a.y + b.y, 0.f);
    float m2 = fmaxf(a.z + b.z, 0.f);
    float m3 = fmaxf(a.w + b.w, 0.f);
    float* p = acc + (size_t)dst * DIM + q * 4;
    if (m0 > 0.f) atomicAdd(p + 0, m0);
    if (m1 > 0.f) atomicAdd(p + 1, m1);
    if (m2 > 0.f) atomicAdd(p + 2, m2);
    if (m3 > 0.f) atomicAdd(p + 3, m3);
  }
}

// ---------------- fused MLP + LayerNorm + GraphNorm + ReLU + residual ----------------
__global__ __launch_bounds__(512, 2) void k_mlp(
    const float* acc, const float* __restrict__ nh,
    const unsigned char* __restrict__ blob,
    const float* __restrict__ b1v, const float* __restrict__ b2v,
    const float* __restrict__ gam, const float* __restrict__ bet,
    const int* __restrict__ node_id, const int* __restrict__ counts,
    float* outp) {
  __shared__ unsigned char lds[131072];
  const int tid  = threadIdx.x;
  const int lane = tid & 63;
  const int wave = tid >> 6;
  const int l15  = lane & 15;
  const int lhi  = lane >> 4;      // 0..3
  const int swz  = (lane & 7) << 4;

  {
    const uint4* s = (const uint4*)blob;
    uint4* d = (uint4*)lds;
#pragma unroll
    for (int i = 0; i < 16; ++i) d[tid + i * 512] = s[tid + i * 512];
  }
  __syncthreads();

  const int row0 = blockIdx.x * 128 + wave * 16;
  const int arow = row0 + l15;
  const bool aok = arow < N_NODES;
  const float* ap = acc + (size_t)arow * DIM + lhi * 8;
  const float* np = nh + (size_t)arow * DIM + lhi * 8;

  // ---- GEMM1: [16x128] x [128x256] ----
  f32x4 c1[16];
#pragma unroll
  for (int i = 0; i < 16; ++i) c1[i] = (f32x4){0.f, 0.f, 0.f, 0.f};

#pragma unroll
  for (int ks = 0; ks < 4; ++ks) {
    bf16x8 af;
    if (aok) {
      float4 x0 = *(const float4*)(ap + ks * 32);
      float4 x1 = *(const float4*)(ap + ks * 32 + 4);
      float4 y0 = *(const float4*)(np + ks * 32);
      float4 y1 = *(const float4*)(np + ks * 32 + 4);
      af[0] = (short)f2bf(x0.x + y0.x);
      af[1] = (short)f2bf(x0.y + y0.y);
      af[2] = (short)f2bf(x0.z + y0.z);
      af[3] = (short)f2bf(x0.w + y0.w);
      af[4] = (short)f2bf(x1.x + y1.x);
      af[5] = (short)f2bf(x1.y + y1.y);
      af[6] = (short)f2bf(x1.z + y1.z);
      af[7] = (short)f2bf(x1.w + y1.w);
    } else {
#pragma unroll
      for (int j = 0; j < 8; ++j) af[j] = 0;
    }
#pragma unroll
    for (int ct = 0; ct < 16; ++ct) {
      int c = ct * 16 + l15;
      const bf16x8* bp = (const bf16x8*)(lds + c * 256 + ((ks * 64 + lhi * 16) ^ swz));
      c1[ct] = __builtin_amdgcn_mfma_f32_16x16x32_bf16(af, *bp, c1[ct], 0, 0, 0);
    }
  }
  __syncthreads();

  // ---- h1 = relu(c1 + b1) -> bf16, swizzled, per-wave LDS region ----
  unsigned char* hb = lds + wave * 8192; // 16 rows x 512B
#pragma unroll
  for (int ct = 0; ct < 16; ++ct) {
    int c = ct * 16 + l15;
    float bb = b1v[c];
#pragma unroll
    for (int i = 0; i < 4; ++i) {
      int r = lhi * 4 + i;
      float v = fmaxf(c1[ct][i] + bb, 0.f);
      *(unsigned short*)(hb + r * 512 + ((2 * c) ^ ((r & 7) << 4))) = f2bf(v);
    }
  }
  __syncthreads();

  // ---- GEMM2: [16x256] x [256x128] ----
  f32x4 c2[8];
#pragma unroll
  for (int i = 0; i < 8; ++i) c2[i] = (f32x4){0.f, 0.f, 0.f, 0.f};

#pragma unroll
  for (int ks = 0; ks < 8; ++ks) {
    bf16x8 af = *(const bf16x8*)(hb + l15 * 512 + ((ks * 64 + lhi * 16) ^ swz));
#pragma unroll
    for (int ct = 0; ct < 8; ++ct) {
      int c = ct * 16 + l15;
      const bf16x8* bp = (const bf16x8*)(lds + 65536 + c * 512 + ((ks * 64 + lhi * 16) ^ swz));
      c2[ct] = __builtin_amdgcn_mfma_f32_16x16x32_bf16(af, *bp, c2[ct], 0, 0, 0);
    }
  }

  // ---- epilogue ----
  float vbuf[8][4];
  float s[4] = {0.f, 0.f, 0.f, 0.f}, sq[4] = {0.f, 0.f, 0.f, 0.f};
#pragma unroll
  for (int ct = 0; ct < 8; ++ct) {
    float bb = b2v[ct * 16 + l15];
#pragma unroll
    for (int i = 0; i < 4; ++i) {
      float x = c2[ct][i] + bb;
      vbuf[ct][i] = x;
      s[i] += x;
      sq[i] += x * x;
    }
  }
#pragma unroll
  for (int m = 1; m <= 8; m <<= 1) {
#pragma unroll
    for (int i = 0; i < 4; ++i) {
      s[i] += __shfl_xor(s[i], m, 64);
      sq[i] += __shfl_xor(sq[i], m, 64);
    }
  }
  float mu[4], rstd[4], gs[4];
  int rr[4];
  bool rok[4];
#pragma unroll
  for (int i = 0; i < 4; ++i) {
    mu[i] = s[i] * (1.f / 128.f);
    float var = sq[i] * (1.f / 128.f) - mu[i] * mu[i];
    rstd[i] = rsqrtf(var + LN_EPS);
    rr[i] = row0 + lhi * 4 + i;
    rok[i] = rr[i] < N_NODES;
    int g = rok[i] ? node_id[rr[i]] : 0;
    gs[i] = rsqrtf(fmaxf((float)counts[g], 1.f));
  }
#pragma unroll
  for (int ct = 0; ct < 8; ++ct) {
    int c = ct * 16 + l15;
    float gg = gam[c], be = bet[c];
#pragma unroll
    for (int i = 0; i < 4; ++i) {
      if (rok[i]) {
        float y = (vbuf[ct][i] - mu[i]) * rstd[i] * gg + be;
        y *= gs[i];
        y = fmaxf(y, 0.f);
        y += nh[(size_t)rr[i] * DIM + c];
        outp[(size_t)rr[i] * DIM + c] = y;
      }
    }
  }
}

extern "C" void kernel_launch(void* const* d_in, const int* in_sizes, int n_in,
                              void* d_out, int out_size, void* d_ws, size_t ws_size,
                              hipStream_t stream) {
  const float* node_hidden = (const float*)d_in[0];
  const float* edge_hidden = (const float*)d_in[1];
  const float* W1  = (const float*)d_in[2];
  const float* b1  = (const float*)d_in[3];
  const float* W2  = (const float*)d_in[4];
  const float* b2  = (const float*)d_in[5];
  const float* lng = (const float*)d_in[6];
  const float* lnb = (const float*)d_in[7];
  const int* edge_index = (const int*)d_in[8];
  const int* node_id    = (const int*)d_in[9];
  float* out = (float*)d_out;

  unsigned char* ws = (unsigned char*)d_ws;
  unsigned char* blob = ws;                       // [0, 128K)
  int* counts   = (int*)(ws + 131072);            // 2KB
  int* ovf_cnt  = (int*)(ws + 133120);            // 4B
  int* ovf_list = (int*)(ws + 133184);            // 16KB
  int* deg      = (int*)(ws + 163840);            // 200KB
  int* slots    = (int*)(ws + 393216);            // 50000*40*4 = 8MB

  k_init<<<196, 256, 0, stream>>>(deg, counts, ovf_cnt);
  k_prep_weights<<<32, 256, 0, stream>>>(W1, W2, blob);
  k_scatter<<<2344, 256, 0, stream>>>(edge_index, node_id, deg, slots,
                                      counts, ovf_cnt, ovf_list);
  k_gather<<<12500, 256, 0, stream>>>((const float2*)node_hidden,
                                      (const float2*)edge_hidden,
                                      edge_index, deg, slots, (float2*)out);
  k_ovf<<<16, 256, 0, stream>>>(ovf_list, ovf_cnt, (const float4*)node_hidden,
                                (const float4*)edge_hidden, edge_index, out);
  k_mlp<<<391, 512, 0, stream>>>(out, node_hidden, blob, b1, b2, lng, lnb,
                                 node_id, counts, out);
}

// Round 4
// 207.309 us; speedup vs baseline: 5.0140x; 1.0396x over previous
//
#include <hip/hip_runtime.h>
#include <hip/hip_bf16.h>

#define N_NODES 50000
#define N_EDGES 600000
#define DIM     128
#define HID     256
#define NGRAPH  512
#define LN_EPS  1e-5f
#define CAP     40      // slot capacity per node (Poisson(12) degree; fallback below)
#define OVFCAP  4096

typedef __attribute__((ext_vector_type(8))) short bf16x8;
typedef __attribute__((ext_vector_type(4))) float f32x4;

__device__ __forceinline__ unsigned short f2bf(float x) {
  unsigned int u = __builtin_bit_cast(unsigned int, x);
  unsigned int r = (u + 0x7FFFu + ((u >> 16) & 1u)) >> 16;
  return (unsigned short)r;
}

// ---------------- init (deg/counts/ovf) + weight prep fused ----------------
// blob layout:
//   [0, 65536):      W1T row c (0..255), 128 bf16/row, byte = c*256 + ((2k)^((c&7)<<4))
//   [65536, 131072): W2T row c (0..127), 256 bf16/row, byte = 65536 + c*512 + ((2k)^((c&7)<<4))
__global__ void k_init_prep(const float* __restrict__ W1, const float* __restrict__ W2,
                            unsigned char* __restrict__ blob,
                            int* __restrict__ deg, int* __restrict__ counts,
                            int* __restrict__ ovf_cnt) {
  int id = blockIdx.x * 256 + threadIdx.x;
  if (id < N_NODES) deg[id] = 0;
  if (id < NGRAPH) counts[id] = 0;
  if (id == 0) *ovf_cnt = 0;
  union { unsigned short s[8]; uint4 v; } u;
  if (id < 4096) {
    int c  = id >> 4;        // 0..255
    int k0 = (id & 15) * 8;  // 0..120
#pragma unroll
    for (int j = 0; j < 8; ++j) u.s[j] = f2bf(W1[(size_t)(k0 + j) * HID + c]);
    unsigned char* dst = blob + c * 256 + ((k0 * 2) ^ ((c & 7) << 4));
    *(uint4*)dst = u.v;
  } else if (id < 8192) {
    int id2 = id - 4096;
    int c  = id2 >> 5;        // 0..127
    int k0 = (id2 & 31) * 8;  // 0..248
#pragma unroll
    for (int j = 0; j < 8; ++j) u.s[j] = f2bf(W2[(size_t)(k0 + j) * DIM + c]);
    unsigned char* dst = blob + 65536 + c * 512 + ((k0 * 2) ^ ((c & 7) << 4));
    *(uint4*)dst = u.v;
  }
}

// ---------------- bucket build: slot = (edge, src) ----------------
__global__ void k_scatter(const int* __restrict__ ei, const int* __restrict__ node_id,
                          int* __restrict__ deg, int2* __restrict__ slots2,
                          int* __restrict__ counts, int* __restrict__ ovf_cnt,
                          int* __restrict__ ovf_list) {
  int t = blockIdx.x * 256 + threadIdx.x;
  if (t < N_NODES) atomicAdd(&counts[node_id[t]], 1);
  if (t < N_EDGES) {
    int src = ei[t];
    int dst = ei[N_EDGES + t];
    int pos = atomicAdd(&deg[dst], 1);
    if (pos < CAP) {
      slots2[(size_t)dst * CAP + pos] = make_int2(t, src);
    } else {
      int o = atomicAdd(ovf_cnt, 1);
      if (o < OVFCAP) ovf_list[o] = t;
    }
  }
}

// ---------------- gather: h[n] = nh[n] + sum_{e->n} relu(nh[src]+eh[e]) ----------------
// 2 nodes per wave: lanes 0-31 -> node A, lanes 32-63 -> node B; float4/lane = 512B/row
__global__ __launch_bounds__(256) void k_gather(
    const f32x4* __restrict__ nh4, const f32x4* __restrict__ eh4,
    const int* __restrict__ deg, const int2* __restrict__ slots2,
    f32x4* __restrict__ out4) {
  int w    = blockIdx.x * 4 + (threadIdx.x >> 6);
  int lane = threadIdx.x & 63;
  int l31  = lane & 31;
  int base = lane & 32;            // half * 32
  int node = w * 2 + (lane >> 5);  // grid sized so node < N_NODES always
  int d = deg[node];
  if (d > CAP) d = CAP;
  // preload slots into regs: s0 covers i<32 (lane l31 = slot l31), s1 covers i in [32,40)
  int2 s0 = make_int2(0, 0), s1 = make_int2(0, 0);
  const int2* sp = slots2 + (size_t)node * CAP;
  if (l31 < d) s0 = sp[l31];
  if (l31 < 8 && 32 + l31 < d) s1 = sp[32 + l31];
  int dmax = max(d, __shfl(d, lane ^ 32));
  f32x4 acc = nh4[(size_t)node * 32 + l31];   // h starts at own nh row
#pragma unroll 2
  for (int i = 0; i < dmax; ++i) {
    int ee, ss;
    if (i < 32) {
      ee = __shfl(s0.x, base + i);
      ss = __shfl(s0.y, base + i);
    } else {
      ee = __shfl(s1.x, base + (i - 32));
      ss = __shfl(s1.y, base + (i - 32));
    }
    if (i < d) {
      f32x4 x = nh4[(size_t)ss * 32 + l31];
      f32x4 y = __builtin_nontemporal_load(&eh4[(size_t)ee * 32 + l31]);
      acc.x += fmaxf(x.x + y.x, 0.f);
      acc.y += fmaxf(x.y + y.y, 0.f);
      acc.z += fmaxf(x.z + y.z, 0.f);
      acc.w += fmaxf(x.w + y.w, 0.f);
    }
  }
  out4[(size_t)node * 32 + l31] = acc;
}

// ---------------- overflow fallback (expected count: 0) ----------------
__global__ void k_ovf(const int* __restrict__ ovf_list, const int* __restrict__ ovf_cnt,
                      const float4* __restrict__ nh4, const float4* __restrict__ eh4,
                      const int* __restrict__ ei, float* __restrict__ acc) {
  int cnt = *ovf_cnt;
  if (cnt > OVFCAP) cnt = OVFCAP;
  int t = blockIdx.x * 256 + threadIdx.x;
  int q = t & 31;
  for (int idx = t >> 5; idx < cnt; idx += (16 * 256) >> 5) {
    int e = ovf_list[idx];
    int src = ei[e];
    int dst = ei[N_EDGES + e];
    float4 a = nh4[(size_t)src * 32 + q];
    float4 b = eh4[(size_t)e * 32 + q];
    float m0 = fmaxf(a.x + b.x, 0.f);
    float m1 = fmaxf(a.y + b.y, 0.f);
    float m2 = fmaxf(a.z + b.z, 0.f);
    float m3 = fmaxf(a.w + b.w, 0.f);
    float* p = acc + (size_t)dst * DIM + q * 4;
    if (m0 > 0.f) atomicAdd(p + 0, m0);
    if (m1 > 0.f) atomicAdd(p + 1, m1);
    if (m2 > 0.f) atomicAdd(p + 2, m2);
    if (m3 > 0.f) atomicAdd(p + 3, m3);
  }
}

// ---------------- fused MLP + LayerNorm + GraphNorm + ReLU + residual ----------------
// acc (= d_out, in place): rows already contain h = nh + agg
__global__ __launch_bounds__(512, 2) void k_mlp(
    const float* acc, const float* __restrict__ nh,
    const unsigned char* __restrict__ blob,
    const float* __restrict__ b1v, const float* __restrict__ b2v,
    const float* __restrict__ gam, const float* __restrict__ bet,
    const int* __restrict__ node_id, const int* __restrict__ counts,
    float* outp) {
  __shared__ unsigned char lds[131072];
  const int tid  = threadIdx.x;
  const int lane = tid & 63;
  const int wave = tid >> 6;
  const int l15  = lane & 15;
  const int lhi  = lane >> 4;      // 0..3
  const int swz  = (lane & 7) << 4;

  {
    const uint4* s = (const uint4*)blob;
    uint4* d = (uint4*)lds;
#pragma unroll
    for (int i = 0; i < 16; ++i) d[tid + i * 512] = s[tid + i * 512];
  }
  __syncthreads();

  const int row0 = blockIdx.x * 128 + wave * 16;
  const int arow = row0 + l15;
  const bool aok = arow < N_NODES;
  const float* ap = acc + (size_t)arow * DIM + lhi * 8;

  // ---- GEMM1: [16x128] x [128x256] ----
  f32x4 c1[16];
#pragma unroll
  for (int i = 0; i < 16; ++i) c1[i] = (f32x4){0.f, 0.f, 0.f, 0.f};

#pragma unroll
  for (int ks = 0; ks < 4; ++ks) {
    bf16x8 af;
    if (aok) {
      float4 x0 = *(const float4*)(ap + ks * 32);
      float4 x1 = *(const float4*)(ap + ks * 32 + 4);
      af[0] = (short)f2bf(x0.x);
      af[1] = (short)f2bf(x0.y);
      af[2] = (short)f2bf(x0.z);
      af[3] = (short)f2bf(x0.w);
      af[4] = (short)f2bf(x1.x);
      af[5] = (short)f2bf(x1.y);
      af[6] = (short)f2bf(x1.z);
      af[7] = (short)f2bf(x1.w);
    } else {
#pragma unroll
      for (int j = 0; j < 8; ++j) af[j] = 0;
    }
#pragma unroll
    for (int ct = 0; ct < 16; ++ct) {
      int c = ct * 16 + l15;
      const bf16x8* bp = (const bf16x8*)(lds + c * 256 + ((ks * 64 + lhi * 16) ^ swz));
      c1[ct] = __builtin_amdgcn_mfma_f32_16x16x32_bf16(af, *bp, c1[ct], 0, 0, 0);
    }
  }
  __syncthreads();

  // ---- h1 = relu(c1 + b1) -> bf16, swizzled, per-wave LDS region ----
  unsigned char* hb = lds + wave * 8192; // 16 rows x 512B
#pragma unroll
  for (int ct = 0; ct < 16; ++ct) {
    int c = ct * 16 + l15;
    float bb = b1v[c];
#pragma unroll
    for (int i = 0; i < 4; ++i) {
      int r = lhi * 4 + i;
      float v = fmaxf(c1[ct][i] + bb, 0.f);
      *(unsigned short*)(hb + r * 512 + ((2 * c) ^ ((r & 7) << 4))) = f2bf(v);
    }
  }
  __syncthreads();

  // ---- GEMM2: [16x256] x [256x128] ----
  f32x4 c2[8];
#pragma unroll
  for (int i = 0; i < 8; ++i) c2[i] = (f32x4){0.f, 0.f, 0.f, 0.f};

#pragma unroll
  for (int ks = 0; ks < 8; ++ks) {
    bf16x8 af = *(const bf16x8*)(hb + l15 * 512 + ((ks * 64 + lhi * 16) ^ swz));
#pragma unroll
    for (int ct = 0; ct < 8; ++ct) {
      int c = ct * 16 + l15;
      const bf16x8* bp = (const bf16x8*)(lds + 65536 + c * 512 + ((ks * 64 + lhi * 16) ^ swz));
      c2[ct] = __builtin_amdgcn_mfma_f32_16x16x32_bf16(af, *bp, c2[ct], 0, 0, 0);
    }
  }

  // ---- epilogue ----
  float vbuf[8][4];
  float s[4] = {0.f, 0.f, 0.f, 0.f}, sq[4] = {0.f, 0.f, 0.f, 0.f};
#pragma unroll
  for (int ct = 0; ct < 8; ++ct) {
    float bb = b2v[ct * 16 + l15];
#pragma unroll
    for (int i = 0; i < 4; ++i) {
      float x = c2[ct][i] + bb;
      vbuf[ct][i] = x;
      s[i] += x;
      sq[i] += x * x;
    }
  }
#pragma unroll
  for (int m = 1; m <= 8; m <<= 1) {
#pragma unroll
    for (int i = 0; i < 4; ++i) {
      s[i] += __shfl_xor(s[i], m, 64);
      sq[i] += __shfl_xor(sq[i], m, 64);
    }
  }
  float mu[4], rstd[4], gs[4];
  int rr[4];
  bool rok[4];
#pragma unroll
  for (int i = 0; i < 4; ++i) {
    mu[i] = s[i] * (1.f / 128.f);
    float var = sq[i] * (1.f / 128.f) - mu[i] * mu[i];
    rstd[i] = rsqrtf(var + LN_EPS);
    rr[i] = row0 + lhi * 4 + i;
    rok[i] = rr[i] < N_NODES;
    int g = rok[i] ? node_id[rr[i]] : 0;
    gs[i] = rsqrtf(fmaxf((float)counts[g], 1.f));
  }
#pragma unroll
  for (int ct = 0; ct < 8; ++ct) {
    int c = ct * 16 + l15;
    float gg = gam[c], be = bet[c];
#pragma unroll
    for (int i = 0; i < 4; ++i) {
      if (rok[i]) {
        float y = (vbuf[ct][i] - mu[i]) * rstd[i] * gg + be;
        y *= gs[i];
        y = fmaxf(y, 0.f);
        y += nh[(size_t)rr[i] * DIM + c];
        outp[(size_t)rr[i] * DIM + c] = y;
      }
    }
  }
}

extern "C" void kernel_launch(void* const* d_in, const int* in_sizes, int n_in,
                              void* d_out, int out_size, void* d_ws, size_t ws_size,
                              hipStream_t stream) {
  const float* node_hidden = (const float*)d_in[0];
  const float* edge_hidden = (const float*)d_in[1];
  const float* W1  = (const float*)d_in[2];
  const float* b1  = (const float*)d_in[3];
  const float* W2  = (const float*)d_in[4];
  const float* b2  = (const float*)d_in[5];
  const float* lng = (const float*)d_in[6];
  const float* lnb = (const float*)d_in[7];
  const int* edge_index = (const int*)d_in[8];
  const int* node_id    = (const int*)d_in[9];
  float* out = (float*)d_out;

  unsigned char* ws = (unsigned char*)d_ws;
  unsigned char* blob = ws;                       // [0, 128K)
  int* counts   = (int*)(ws + 131072);            // 2KB
  int* ovf_cnt  = (int*)(ws + 133120);            // 4B
  int* ovf_list = (int*)(ws + 133184);            // 16KB
  int* deg      = (int*)(ws + 163840);            // 200KB
  int2* slots2  = (int2*)(ws + 393216);           // 50000*40*8 = 16MB

  k_init_prep<<<196, 256, 0, stream>>>(W1, W2, blob, deg, counts, ovf_cnt);
  k_scatter<<<2344, 256, 0, stream>>>(edge_index, node_id, deg, slots2,
                                      counts, ovf_cnt, ovf_list);
  k_gather<<<6250, 256, 0, stream>>>((const f32x4*)node_hidden,
                                     (const f32x4*)edge_hidden,
                                     deg, slots2, (f32x4*)out);
  k_ovf<<<16, 256, 0, stream>>>(ovf_list, ovf_cnt, (const float4*)node_hidden,
                                (const float4*)edge_hidden, edge_index, out);
  k_mlp<<<391, 512, 0, stream>>>(out, node_hidden, blob, b1, b2, lng, lnb,
                                 node_id, counts, out);
}